// Round 5
// baseline (159.324 us; speedup 1.0000x reference)
//
#include <hip/hip_runtime.h>
#include <math.h>

#define BB 16
#define CIN 64
#define HH 64
#define WW 64
#define COUT 128
#define HW 4096          // HH*WW
#define CK 576           // CIN*9
#define CKP 584          // padded LDS stride (shorts)

typedef __attribute__((ext_vector_type(8))) short short8;
typedef __attribute__((ext_vector_type(4))) short short4v;
typedef __attribute__((ext_vector_type(4))) float f32x4;

// ---- workspace layout (float indices) ----
#define OFF_OFF   0                         // B*18*HW  = 1179648 floats
#define MASK_OFF  1179648                   // B*9*HW   = 589824 floats
#define WT_OFF    1769472                   // CK*COUT shorts = 36864 floats
#define WPM_OFF   1806336                   // 32*CK shorts = 9216 floats
#define XH_OFF    1815552                   // B*HW*CIN shorts = 8388608 floats
#define SAB_OFF   10204160                  // 256 floats (A,B per channel)
#define STAT_OFF  10204416                  // 256 floats (sum,sumsq accum)
// total ~40.8 MB. y lives in d_out.

__device__ __forceinline__ short f2bf(float f) {
    union { float f; unsigned u; } cv; cv.f = f;
    unsigned u = cv.u;
    unsigned r = (u + 0x7fffu + ((u >> 16) & 1u)) >> 16;
    return (short)r;
}
__device__ __forceinline__ float bf2f(short s) {
    union { unsigned u; float f; } cv;
    cv.u = ((unsigned)(unsigned short)s) << 16;
    return cv.f;
}

// ---------------------------------------------------------------------------
// Kernel A: transpose x NCHW -> NHWC bf16 (xh[b][y][x][c])
__global__ __launch_bounds__(256) void k_nhwc(const float* __restrict__ x,
                                              short* __restrict__ xh) {
    __shared__ float t[64][65];
    const int blk  = blockIdx.x;          // 1024 = 16 b * 64 pos-groups
    const int b    = blk >> 6;
    const int pos0 = (blk & 63) << 6;
    const int a    = threadIdx.x & 63;
    const int q    = threadIdx.x >> 6;    // 0..3
#pragma unroll
    for (int i = 0; i < 16; ++i) {
        int c = i * 4 + q;
        t[c][a] = x[((size_t)(b * CIN + c)) * HW + pos0 + a];
    }
    __syncthreads();
#pragma unroll
    for (int i = 0; i < 16; ++i) {
        int p = i * 4 + q;
        xh[((size_t)b * HW + pos0 + p) * CIN + a] = f2bf(t[a][p]);
    }
}

// ---------------------------------------------------------------------------
// Kernel B: pack weights to bf16, K-order kk = k*64+c.
__global__ __launch_bounds__(256) void k_pack(const float* __restrict__ wd,
                                              const float* __restrict__ wp,
                                              const float* __restrict__ wm,
                                              short* __restrict__ wtb,
                                              short* __restrict__ wpm) {
    int i = blockIdx.x * 256 + threadIdx.x;
    if (i < CK * COUT) {
        int co = i / CK;
        int kk = i - co * CK;
        int k  = kk >> 6;
        int c  = kk & 63;
        wtb[i] = f2bf(wd[co * CK + c * 9 + k]);
        return;
    }
    i -= CK * COUT;
    if (i < 32 * CK) {
        int t  = i / CK;
        int kk = i - t * CK;
        int k  = kk >> 6;
        int c  = kk & 63;
        float v = 0.f;
        if (t < 18)      v = wp[t * CK + c * 9 + k];
        else if (t < 27) v = wm[(t - 18) * CK + c * 9 + k];
        wpm[i] = f2bf(v);
    }
}

// ---------------------------------------------------------------------------
// Kernel 1: offset/mask conv as barrier-free implicit MFMA GEMM.
__global__ __launch_bounds__(256) void k_conv_pm(const short* __restrict__ xh,
                                                 const short* __restrict__ wpm,
                                                 const float* __restrict__ bp,
                                                 const float* __restrict__ bm,
                                                 float* __restrict__ off,
                                                 float* __restrict__ mask) {
    const int bid  = blockIdx.x;                       // 2048
    const int swz  = (bid & 7) * 256 + (bid >> 3);     // XCD-chunked
    const int pos0 = swz * 32;
    const int b   = pos0 >> 12;
    const int ho  = (pos0 >> 6) & 63;
    const int wo0 = pos0 & 63;

    const int tid  = threadIdx.x;
    const int wv   = tid >> 6;
    const int lane = tid & 63;
    const int l15  = lane & 15;
    const int lk   = lane >> 4;
    const int mw   = wv & 1;
    const int nw   = wv >> 1;

    const int p    = mw * 16 + l15;
    const int wo   = wo0 + p;
    const int t    = nw * 16 + l15;

    const short* xb  = xh + (size_t)b * HW * CIN;
    const short* wr  = wpm + t * CK;

    f32x4 acc = (f32x4)(0.f);
#pragma unroll
    for (int kc = 0; kc < 18; ++kc) {
        const int k  = kc >> 1;
        const int c0 = (kc & 1) * 32 + lk * 8;
        const int yy = ho - 1 + k / 3;
        const int xx = wo - 1 + k % 3;
        const bool valid = ((unsigned)yy < 64u) & ((unsigned)xx < 64u);
        const int yyc = min(max(yy, 0), 63);
        const int xxc = min(max(xx, 0), 63);
        short8 a = *(const short8*)&xb[(((yyc << 6) + xxc) << 6) + c0];
        if (!valid) a = (short8)0;
        short8 bfr = *(const short8*)&wr[kc * 32 + lk * 8];
        acc = __builtin_amdgcn_mfma_f32_16x16x32_bf16(a, bfr, acc, 0, 0, 0);
    }

    const int pst = wo0 + mw * 16 + lk * 4;
    if (t < 18) {
        float bias = bp[t];
        float4 o;
        o.x = acc[0] + bias; o.y = acc[1] + bias;
        o.z = acc[2] + bias; o.w = acc[3] + bias;
        *(float4*)&off[(((size_t)b * 18 + t) * HH + ho) * WW + pst] = o;
    } else if (t < 27) {
        float bias = bm[t - 18];
        float4 o;
        o.x = 1.f / (1.f + expf(-(acc[0] + bias)));
        o.y = 1.f / (1.f + expf(-(acc[1] + bias)));
        o.z = 1.f / (1.f + expf(-(acc[2] + bias)));
        o.w = 1.f / (1.f + expf(-(acc[3] + bias)));
        *(float4*)&mask[(((size_t)b * 9 + (t - 18)) * HH + ho) * WW + pst] = o;
    }
}

// ---------------------------------------------------------------------------
// Kernel 2: deformable conv. 512 threads/block, 32-pos tile, fused BN partials.
#define MPB 32
__global__ __launch_bounds__(512) void k_deform(const short* __restrict__ xh,
                                                const float* __restrict__ off,
                                                const float* __restrict__ mask,
                                                const short* __restrict__ wtb,
                                                const float* __restrict__ bd,
                                                float* __restrict__ y,
                                                float* __restrict__ gstat) {
    __shared__ short    val[MPB * CKP];     // 37376 B
    __shared__ unsigned s_yx[MPB * 9];
    __shared__ float    s_w[MPB * 9 * 4];   // reused as 256-float scratch later
    // total 43136 B -> 3 blocks/CU = 24 waves/CU

    const int bid  = blockIdx.x;                       // 2048
    const int swz  = (bid & 7) * 256 + (bid >> 3);     // XCD-chunked
    const int pos0 = swz * MPB;
    const int b   = pos0 >> 12;
    const int ho  = (pos0 >> 6) & 63;
    const int wo0 = pos0 & 63;
    const int tid = threadIdx.x;

    // phase 1: sampling parameters (32 pos x 9 taps)
    if (tid < MPB * 9) {
        int t = tid;
        int p = t / 9, k = t - p * 9;
        int wo = wo0 + p;
        float dy = off[(((size_t)b * 18 + 2 * k    ) * HH + ho) * WW + wo];
        float dx = off[(((size_t)b * 18 + 2 * k + 1) * HH + ho) * WW + wo];
        float m  = mask[(((size_t)b * 9 + k) * HH + ho) * WW + wo];
        float py = (float)(ho - 1 + k / 3) + dy;
        float px = (float)(wo - 1 + k % 3) + dx;
        float fy = floorf(py), fx = floorf(px);
        float ly = py - fy, lx = px - fx;
        int y0 = (int)fy, x0 = (int)fx;
        int y1 = y0 + 1, x1 = x0 + 1;
        float vy0 = ((unsigned)y0 < 64u) ? 1.f : 0.f;
        float vy1 = ((unsigned)y1 < 64u) ? 1.f : 0.f;
        float vx0 = ((unsigned)x0 < 64u) ? 1.f : 0.f;
        float vx1 = ((unsigned)x1 < 64u) ? 1.f : 0.f;
        int y0c = min(max(y0, 0), 63), y1c = min(max(y1, 0), 63);
        int x0c = min(max(x0, 0), 63), x1c = min(max(x1, 0), 63);
        s_yx[t] = (unsigned)y0c | ((unsigned)y1c << 8) | ((unsigned)x0c << 16) | ((unsigned)x1c << 24);
        s_w[t * 4 + 0] = (1.f - ly) * (1.f - lx) * m * vy0 * vx0;
        s_w[t * 4 + 1] = (1.f - ly) * lx * m * vy0 * vx1;
        s_w[t * 4 + 2] = ly * (1.f - lx) * m * vy1 * vx0;
        s_w[t * 4 + 3] = ly * lx * m * vy1 * vx1;
    }
    __syncthreads();

    // phase 2: gather, 32 tap-groups in flight; lane li -> channels li*4..+3
    {
        const int g  = tid >> 4;            // 0..31
        const int li = tid & 15;
        const int c0 = li * 4;
        const short* xb = xh + (size_t)b * HW * CIN;
#pragma unroll 3
        for (int it = 0; it < 9; ++it) {
            int pr = it * 32 + g;           // 0..287
            int p = pr / 9, k = pr - p * 9;
            unsigned yx = s_yx[pr];
            int y0 = yx & 255, y1 = (yx >> 8) & 255;
            int x0 = (yx >> 16) & 255, x1 = yx >> 24;
            float w0 = s_w[pr * 4 + 0], w1 = s_w[pr * 4 + 1];
            float w2 = s_w[pr * 4 + 2], w3 = s_w[pr * 4 + 3];
            short4v v00 = *(const short4v*)&xb[(((y0 << 6) + x0) << 6) + c0];
            short4v v01 = *(const short4v*)&xb[(((y0 << 6) + x1) << 6) + c0];
            short4v v10 = *(const short4v*)&xb[(((y1 << 6) + x0) << 6) + c0];
            short4v v11 = *(const short4v*)&xb[(((y1 << 6) + x1) << 6) + c0];
            short4v o;
#pragma unroll
            for (int j = 0; j < 4; ++j) {
                float f = w0 * bf2f(v00[j]) + w1 * bf2f(v01[j])
                        + w2 * bf2f(v10[j]) + w3 * bf2f(v11[j]);
                o[j] = f2bf(f);
            }
            *(short4v*)&val[p * CKP + (k << 6) + c0] = o;
        }
    }
    __syncthreads();

    // phase 3: MFMA GEMM, 8 waves; wave = (position half mw, channel quarter nq)
    const int wv   = tid >> 6;
    const int lane = tid & 63;
    const int l15  = lane & 15;
    const int lk   = lane >> 4;
    const int mw   = wv & 1;
    const int nq   = wv >> 1;              // 0..3 -> channels nq*32..nq*32+31

    f32x4 acc[2];
    acc[0] = (f32x4)(0.f);
    acc[1] = (f32x4)(0.f);

    const short* wrow0 = wtb + (size_t)(nq * 32 + l15) * CK + lk * 8;
    const short* wrow1 = wrow0 + 16 * CK;
    const int arow = (mw * 16 + l15) * CKP + lk * 8;
#pragma unroll
    for (int kc = 0; kc < 18; ++kc) {
        short8 a  = *(const short8*)&val[arow + kc * 32];
        short8 b0 = *(const short8*)&wrow0[kc * 32];
        short8 b1 = *(const short8*)&wrow1[kc * 32];
        acc[0] = __builtin_amdgcn_mfma_f32_16x16x32_bf16(a, b0, acc[0], 0, 0, 0);
        acc[1] = __builtin_amdgcn_mfma_f32_16x16x32_bf16(a, b1, acc[1], 0, 0, 0);
    }

    // epilogue: write y (+bias), and per-wave BN partial reduction
    float s[2], q[2];
#pragma unroll
    for (int n = 0; n < 2; ++n) {
        int co = nq * 32 + n * 16 + l15;
        int p  = mw * 16 + lk * 4;
        float bias = bd[co];
        float4 o;
        o.x = acc[n][0] + bias;
        o.y = acc[n][1] + bias;
        o.z = acc[n][2] + bias;
        o.w = acc[n][3] + bias;
        *(float4*)&y[((size_t)(b * COUT + co)) * HW + ho * WW + wo0 + p] = o;
        // stats on pre-bias acc (bias folded in finalize)
        float ls = acc[n][0] + acc[n][1] + acc[n][2] + acc[n][3];
        float lq = acc[n][0]*acc[n][0] + acc[n][1]*acc[n][1]
                 + acc[n][2]*acc[n][2] + acc[n][3]*acc[n][3];
        ls += __shfl_xor(ls, 16); ls += __shfl_xor(ls, 32);
        lq += __shfl_xor(lq, 16); lq += __shfl_xor(lq, 32);
        s[n] = ls; q[n] = lq;                 // valid on all lanes
    }
    float* scratch = s_w;                     // reuse (phase-2 data dead)
    __syncthreads();
    if (mw == 0 && lane < 16) {
#pragma unroll
        for (int n = 0; n < 2; ++n) {
            int co = nq * 32 + n * 16 + l15;
            scratch[co]       = s[n];
            scratch[128 + co] = q[n];
        }
    }
    __syncthreads();
    if (mw == 1 && lane < 16) {
#pragma unroll
        for (int n = 0; n < 2; ++n) {
            int co = nq * 32 + n * 16 + l15;
            atomicAdd(&gstat[co],       s[n] + scratch[co]);
            atomicAdd(&gstat[128 + co], q[n] + scratch[128 + co]);
        }
    }
}

// ---------------------------------------------------------------------------
// Kernel 3: finalize BN scale/shift from accumulated moments
__global__ __launch_bounds__(128) void k_finalize(const float* __restrict__ gstat,
                                                  const float* __restrict__ bd,
                                                  const float* __restrict__ gamma,
                                                  const float* __restrict__ beta,
                                                  float* __restrict__ sAB) {
    int c = threadIdx.x;
    const float invN = 1.f / (float)(BB * HW);
    float mean_acc = gstat[c] * invN;
    float var = gstat[128 + c] * invN - mean_acc * mean_acc;
    float mean_y = mean_acc + bd[c];
    float A = gamma[c] * rsqrtf(var + 1e-5f);
    sAB[c]       = A;
    sAB[128 + c] = beta[c] - mean_y * A;
}

// ---------------------------------------------------------------------------
// Kernel 4: normalize + exact GELU (in-place on d_out)
__global__ __launch_bounds__(256) void k_norm_gelu(float* __restrict__ y,
                                                   const float* __restrict__ sAB) {
    int i4 = blockIdx.x * 256 + threadIdx.x;
    if (i4 >= (BB * COUT * HW) / 4) return;
    int c = (i4 >> 10) & 127;
    float A  = sAB[c];
    float Bc = sAB[128 + c];
    float4 v = ((const float4*)y)[i4];
    float4 r;
    float t;
    t = v.x * A + Bc; r.x = 0.5f * t * (1.f + erff(t * 0.70710678118654752f));
    t = v.y * A + Bc; r.y = 0.5f * t * (1.f + erff(t * 0.70710678118654752f));
    t = v.z * A + Bc; r.z = 0.5f * t * (1.f + erff(t * 0.70710678118654752f));
    t = v.w * A + Bc; r.w = 0.5f * t * (1.f + erff(t * 0.70710678118654752f));
    ((float4*)y)[i4] = r;
}

// ---------------------------------------------------------------------------
extern "C" void kernel_launch(void* const* d_in, const int* in_sizes, int n_in,
                              void* d_out, int out_size, void* d_ws, size_t ws_size,
                              hipStream_t stream) {
    const float* x     = (const float*)d_in[0];
    const float* w_p   = (const float*)d_in[1];
    const float* b_p   = (const float*)d_in[2];
    const float* w_m   = (const float*)d_in[3];
    const float* b_m   = (const float*)d_in[4];
    const float* w_d   = (const float*)d_in[5];
    const float* b_d   = (const float*)d_in[6];
    const float* gamma = (const float*)d_in[7];
    const float* beta  = (const float*)d_in[8];
    float* ws  = (float*)d_ws;
    float* y   = (float*)d_out;

    float* off  = ws + OFF_OFF;
    float* mask = ws + MASK_OFF;
    short* wtb  = (short*)(ws + WT_OFF);
    short* wpm  = (short*)(ws + WPM_OFF);
    short* xh   = (short*)(ws + XH_OFF);
    float* sAB  = ws + SAB_OFF;
    float* gstat= ws + STAT_OFF;

    hipMemsetAsync(gstat, 0, 256 * sizeof(float), stream);
    k_nhwc<<<dim3(1024), dim3(256), 0, stream>>>(x, xh);
    k_pack<<<dim3((CK * COUT + 32 * CK + 255) / 256), dim3(256), 0, stream>>>(w_d, w_p, w_m, wtb, wpm);
    k_conv_pm<<<dim3(BB * HW / 32), dim3(256), 0, stream>>>(xh, wpm, b_p, b_m, off, mask);
    k_deform<<<dim3(BB * HW / MPB), dim3(512), 0, stream>>>(xh, off, mask, wtb, b_d, y, gstat);
    k_finalize<<<dim3(1), dim3(128), 0, stream>>>(gstat, b_d, gamma, beta, sAB);
    k_norm_gelu<<<dim3((BB * COUT * HW / 4 + 255) / 256), dim3(256), 0, stream>>>(y, sAB);
}

// Round 6
// 125.198 us; speedup vs baseline: 1.2726x; 1.2726x over previous
//
#include <hip/hip_runtime.h>
#include <math.h>

#define BB 16
#define CIN 64
#define HH 64
#define WW 64
#define COUT 128
#define HW 4096          // HH*WW
#define CK 576           // CIN*9
#define CKP 584          // padded LDS stride (shorts)

typedef __attribute__((ext_vector_type(8))) short short8;
typedef __attribute__((ext_vector_type(4))) short short4v;
typedef __attribute__((ext_vector_type(4))) float f32x4;

// ---- workspace layout (float indices) ----
#define OFF_OFF   0                         // B*18*HW  = 1179648 floats
#define MASK_OFF  1179648                   // B*9*HW   = 589824 floats
#define WT_OFF    1769472                   // wt2: 18*128*32 shorts = 36864 floats
#define WPM_OFF   1806336                   // wpm2: 18*32*32 shorts = 9216 floats
#define XH_OFF    1815552                   // B*HW*CIN shorts = 8388608 floats
#define SAB_OFF   10204160                  // 256 floats (A,B per channel)
#define STAT_OFF  10204416                  // 256 floats (sum,sumsq accum)
// total ~40.8 MB. y lives in d_out.

__device__ __forceinline__ short f2bf(float f) {
    union { float f; unsigned u; } cv; cv.f = f;
    unsigned u = cv.u;
    unsigned r = (u + 0x7fffu + ((u >> 16) & 1u)) >> 16;
    return (short)r;
}
__device__ __forceinline__ float bf2f(short s) {
    union { unsigned u; float f; } cv;
    cv.u = ((unsigned)(unsigned short)s) << 16;
    return cv.f;
}

// ---------------------------------------------------------------------------
// Kernel A: transpose x NCHW -> NHWC bf16 (xh[b][y][x][c])
__global__ __launch_bounds__(256) void k_nhwc(const float* __restrict__ x,
                                              short* __restrict__ xh) {
    __shared__ float t[64][65];
    const int blk  = blockIdx.x;          // 1024 = 16 b * 64 pos-groups
    const int b    = blk >> 6;
    const int pos0 = (blk & 63) << 6;
    const int a    = threadIdx.x & 63;
    const int q    = threadIdx.x >> 6;    // 0..3
#pragma unroll
    for (int i = 0; i < 16; ++i) {
        int c = i * 4 + q;
        t[c][a] = x[((size_t)(b * CIN + c)) * HW + pos0 + a];
    }
    __syncthreads();
#pragma unroll
    for (int i = 0; i < 16; ++i) {
        int p = i * 4 + q;
        xh[((size_t)b * HW + pos0 + p) * CIN + a] = f2bf(t[a][p]);
    }
}

// ---------------------------------------------------------------------------
// Kernel B: pack weights to bf16, K-MAJOR panels for coalesced B-fragments.
//  wt2 [kc][co][kl]  : kc=kk>>5 (kk=k*64+c), co<128, kl=kk&31
//  wpm2[kc][t ][kl]  : t<18 w_p, 18<=t<27 w_m, else 0
__global__ __launch_bounds__(256) void k_pack(const float* __restrict__ wd,
                                              const float* __restrict__ wp,
                                              const float* __restrict__ wm,
                                              short* __restrict__ wt2,
                                              short* __restrict__ wpm2) {
    int i = blockIdx.x * 256 + threadIdx.x;
    if (i < 18 * 128 * 32) {
        int kc  = i >> 12;
        int rem = i & 4095;
        int co  = rem >> 5;
        int kl  = rem & 31;
        int kk  = kc * 32 + kl;
        int k   = kk >> 6;
        int c   = kk & 63;
        wt2[i] = f2bf(wd[co * CK + c * 9 + k]);
        return;
    }
    i -= 18 * 128 * 32;
    if (i < 18 * 32 * 32) {
        int kc  = i >> 10;
        int rem = i & 1023;
        int t   = rem >> 5;
        int kl  = rem & 31;
        int kk  = kc * 32 + kl;
        int k   = kk >> 6;
        int c   = kk & 63;
        float v = 0.f;
        if (t < 18)      v = wp[t * CK + c * 9 + k];
        else if (t < 27) v = wm[(t - 18) * CK + c * 9 + k];
        wpm2[i] = f2bf(v);
    }
}

// ---------------------------------------------------------------------------
// Kernel 1: offset/mask conv as barrier-free implicit MFMA GEMM.
__global__ __launch_bounds__(256) void k_conv_pm(const short* __restrict__ xh,
                                                 const short* __restrict__ wpm2,
                                                 const float* __restrict__ bp,
                                                 const float* __restrict__ bm,
                                                 float* __restrict__ off,
                                                 float* __restrict__ mask) {
    const int bid  = blockIdx.x;                       // 2048
    const int swz  = (bid & 7) * 256 + (bid >> 3);     // XCD-chunked
    const int pos0 = swz * 32;
    const int b   = pos0 >> 12;
    const int ho  = (pos0 >> 6) & 63;
    const int wo0 = pos0 & 63;

    const int tid  = threadIdx.x;
    const int wv   = tid >> 6;
    const int lane = tid & 63;
    const int l15  = lane & 15;
    const int lk   = lane >> 4;
    const int mw   = wv & 1;
    const int nw   = wv >> 1;

    const int p    = mw * 16 + l15;
    const int wo   = wo0 + p;
    const int t    = nw * 16 + l15;

    const short* xb  = xh + (size_t)b * HW * CIN;
    const short* wr  = wpm2 + t * 32 + lk * 8;         // coalesced K-major panels

    f32x4 acc = (f32x4)(0.f);
#pragma unroll
    for (int kc = 0; kc < 18; ++kc) {
        const int k  = kc >> 1;
        const int c0 = (kc & 1) * 32 + lk * 8;
        const int yy = ho - 1 + k / 3;
        const int xx = wo - 1 + k % 3;
        const bool valid = ((unsigned)yy < 64u) & ((unsigned)xx < 64u);
        const int yyc = min(max(yy, 0), 63);
        const int xxc = min(max(xx, 0), 63);
        short8 a = *(const short8*)&xb[(((yyc << 6) + xxc) << 6) + c0];
        if (!valid) a = (short8)0;
        short8 bfr = *(const short8*)&wr[kc * 1024];
        acc = __builtin_amdgcn_mfma_f32_16x16x32_bf16(a, bfr, acc, 0, 0, 0);
    }

    const int pst = wo0 + mw * 16 + lk * 4;
    if (t < 18) {
        float bias = bp[t];
        float4 o;
        o.x = acc[0] + bias; o.y = acc[1] + bias;
        o.z = acc[2] + bias; o.w = acc[3] + bias;
        *(float4*)&off[(((size_t)b * 18 + t) * HH + ho) * WW + pst] = o;
    } else if (t < 27) {
        float bias = bm[t - 18];
        float4 o;
        o.x = 1.f / (1.f + expf(-(acc[0] + bias)));
        o.y = 1.f / (1.f + expf(-(acc[1] + bias)));
        o.z = 1.f / (1.f + expf(-(acc[2] + bias)));
        o.w = 1.f / (1.f + expf(-(acc[3] + bias)));
        *(float4*)&mask[(((size_t)b * 9 + (t - 18)) * HH + ho) * WW + pst] = o;
    }
}

// ---------------------------------------------------------------------------
// Kernel 2: deformable conv. 512 threads/block, 32-pos tile, fused BN partials.
#define MPB 32
__global__ __launch_bounds__(512) void k_deform(const short* __restrict__ xh,
                                                const float* __restrict__ off,
                                                const float* __restrict__ mask,
                                                const short* __restrict__ wt2,
                                                const float* __restrict__ bd,
                                                float* __restrict__ y,
                                                float* __restrict__ gstat) {
    __shared__ short    val[MPB * CKP];     // 37376 B
    __shared__ unsigned s_yx[MPB * 9];
    __shared__ float    s_w[MPB * 9 * 4];   // reused as 256-float scratch later
    // total 43136 B -> 3 blocks/CU

    const int bid  = blockIdx.x;                       // 2048
    const int swz  = (bid & 7) * 256 + (bid >> 3);     // XCD-chunked
    const int pos0 = swz * MPB;
    const int b   = pos0 >> 12;
    const int ho  = (pos0 >> 6) & 63;
    const int wo0 = pos0 & 63;
    const int tid = threadIdx.x;

    // phase 1: sampling parameters (32 pos x 9 taps)
    if (tid < MPB * 9) {
        int t = tid;
        int p = t / 9, k = t - p * 9;
        int wo = wo0 + p;
        float dy = off[(((size_t)b * 18 + 2 * k    ) * HH + ho) * WW + wo];
        float dx = off[(((size_t)b * 18 + 2 * k + 1) * HH + ho) * WW + wo];
        float m  = mask[(((size_t)b * 9 + k) * HH + ho) * WW + wo];
        float py = (float)(ho - 1 + k / 3) + dy;
        float px = (float)(wo - 1 + k % 3) + dx;
        float fy = floorf(py), fx = floorf(px);
        float ly = py - fy, lx = px - fx;
        int y0 = (int)fy, x0 = (int)fx;
        int y1 = y0 + 1, x1 = x0 + 1;
        float vy0 = ((unsigned)y0 < 64u) ? 1.f : 0.f;
        float vy1 = ((unsigned)y1 < 64u) ? 1.f : 0.f;
        float vx0 = ((unsigned)x0 < 64u) ? 1.f : 0.f;
        float vx1 = ((unsigned)x1 < 64u) ? 1.f : 0.f;
        int y0c = min(max(y0, 0), 63), y1c = min(max(y1, 0), 63);
        int x0c = min(max(x0, 0), 63), x1c = min(max(x1, 0), 63);
        s_yx[t] = (unsigned)y0c | ((unsigned)y1c << 8) | ((unsigned)x0c << 16) | ((unsigned)x1c << 24);
        s_w[t * 4 + 0] = (1.f - ly) * (1.f - lx) * m * vy0 * vx0;
        s_w[t * 4 + 1] = (1.f - ly) * lx * m * vy0 * vx1;
        s_w[t * 4 + 2] = ly * (1.f - lx) * m * vy1 * vx0;
        s_w[t * 4 + 3] = ly * lx * m * vy1 * vx1;
    }
    __syncthreads();

    // phase 2: gather, 32 tap-groups in flight; lane li -> channels li*4..+3
    {
        const int g  = tid >> 4;            // 0..31
        const int li = tid & 15;
        const int c0 = li * 4;
        const short* xb = xh + (size_t)b * HW * CIN;
#pragma unroll 3
        for (int it = 0; it < 9; ++it) {
            int pr = it * 32 + g;           // 0..287
            int p = pr / 9, k = pr - p * 9;
            unsigned yx = s_yx[pr];
            int y0 = yx & 255, y1 = (yx >> 8) & 255;
            int x0 = (yx >> 16) & 255, x1 = yx >> 24;
            float w0 = s_w[pr * 4 + 0], w1 = s_w[pr * 4 + 1];
            float w2 = s_w[pr * 4 + 2], w3 = s_w[pr * 4 + 3];
            short4v v00 = *(const short4v*)&xb[(((y0 << 6) + x0) << 6) + c0];
            short4v v01 = *(const short4v*)&xb[(((y0 << 6) + x1) << 6) + c0];
            short4v v10 = *(const short4v*)&xb[(((y1 << 6) + x0) << 6) + c0];
            short4v v11 = *(const short4v*)&xb[(((y1 << 6) + x1) << 6) + c0];
            short4v o;
#pragma unroll
            for (int j = 0; j < 4; ++j) {
                float f = w0 * bf2f(v00[j]) + w1 * bf2f(v01[j])
                        + w2 * bf2f(v10[j]) + w3 * bf2f(v11[j]);
                o[j] = f2bf(f);
            }
            *(short4v*)&val[p * CKP + (k << 6) + c0] = o;
        }
    }
    __syncthreads();

    // phase 3: MFMA GEMM, 8 waves; wave = (position half mw, channel quarter nq)
    const int wv   = tid >> 6;
    const int lane = tid & 63;
    const int l15  = lane & 15;
    const int lk   = lane >> 4;
    const int mw   = wv & 1;
    const int nq   = wv >> 1;              // 0..3 -> channels nq*32..nq*32+31

    f32x4 acc[2];
    acc[0] = (f32x4)(0.f);
    acc[1] = (f32x4)(0.f);

    // K-major wt2: wave reads contiguous 1KB per fragment
    const short* wq = wt2 + (nq * 32 + l15) * 32 + lk * 8;
    const int arow = (mw * 16 + l15) * CKP + lk * 8;
#pragma unroll
    for (int kc = 0; kc < 18; ++kc) {
        short8 a  = *(const short8*)&val[arow + kc * 32];
        short8 b0 = *(const short8*)&wq[kc * 4096];
        short8 b1 = *(const short8*)&wq[kc * 4096 + 512];
        acc[0] = __builtin_amdgcn_mfma_f32_16x16x32_bf16(a, b0, acc[0], 0, 0, 0);
        acc[1] = __builtin_amdgcn_mfma_f32_16x16x32_bf16(a, b1, acc[1], 0, 0, 0);
    }

    // epilogue: write y (+bias), and per-wave BN partial reduction
    float s[2], q[2];
#pragma unroll
    for (int n = 0; n < 2; ++n) {
        int co = nq * 32 + n * 16 + l15;
        int p  = mw * 16 + lk * 4;
        float bias = bd[co];
        float4 o;
        o.x = acc[n][0] + bias;
        o.y = acc[n][1] + bias;
        o.z = acc[n][2] + bias;
        o.w = acc[n][3] + bias;
        *(float4*)&y[((size_t)(b * COUT + co)) * HW + ho * WW + wo0 + p] = o;
        float ls = acc[n][0] + acc[n][1] + acc[n][2] + acc[n][3];
        float lq = acc[n][0]*acc[n][0] + acc[n][1]*acc[n][1]
                 + acc[n][2]*acc[n][2] + acc[n][3]*acc[n][3];
        ls += __shfl_xor(ls, 16); ls += __shfl_xor(ls, 32);
        lq += __shfl_xor(lq, 16); lq += __shfl_xor(lq, 32);
        s[n] = ls; q[n] = lq;
    }
    float* scratch = s_w;                     // reuse (phase-2 data dead)
    __syncthreads();
    if (mw == 0 && lane < 16) {
#pragma unroll
        for (int n = 0; n < 2; ++n) {
            int co = nq * 32 + n * 16 + l15;
            scratch[co]       = s[n];
            scratch[128 + co] = q[n];
        }
    }
    __syncthreads();
    if (mw == 1 && lane < 16) {
#pragma unroll
        for (int n = 0; n < 2; ++n) {
            int co = nq * 32 + n * 16 + l15;
            atomicAdd(&gstat[co],       s[n] + scratch[co]);
            atomicAdd(&gstat[128 + co], q[n] + scratch[128 + co]);
        }
    }
}

// ---------------------------------------------------------------------------
// Kernel 3: finalize BN scale/shift from accumulated moments
__global__ __launch_bounds__(128) void k_finalize(const float* __restrict__ gstat,
                                                  const float* __restrict__ bd,
                                                  const float* __restrict__ gamma,
                                                  const float* __restrict__ beta,
                                                  float* __restrict__ sAB) {
    int c = threadIdx.x;
    const float invN = 1.f / (float)(BB * HW);
    float mean_acc = gstat[c] * invN;
    float var = gstat[128 + c] * invN - mean_acc * mean_acc;
    float mean_y = mean_acc + bd[c];
    float A = gamma[c] * rsqrtf(var + 1e-5f);
    sAB[c]       = A;
    sAB[128 + c] = beta[c] - mean_y * A;
}

// ---------------------------------------------------------------------------
// Kernel 4: normalize + exact GELU (in-place on d_out)
__global__ __launch_bounds__(256) void k_norm_gelu(float* __restrict__ y,
                                                   const float* __restrict__ sAB) {
    int i4 = blockIdx.x * 256 + threadIdx.x;
    if (i4 >= (BB * COUT * HW) / 4) return;
    int c = (i4 >> 10) & 127;
    float A  = sAB[c];
    float Bc = sAB[128 + c];
    float4 v = ((const float4*)y)[i4];
    float4 r;
    float t;
    t = v.x * A + Bc; r.x = 0.5f * t * (1.f + erff(t * 0.70710678118654752f));
    t = v.y * A + Bc; r.y = 0.5f * t * (1.f + erff(t * 0.70710678118654752f));
    t = v.z * A + Bc; r.z = 0.5f * t * (1.f + erff(t * 0.70710678118654752f));
    t = v.w * A + Bc; r.w = 0.5f * t * (1.f + erff(t * 0.70710678118654752f));
    ((float4*)y)[i4] = r;
}

// ---------------------------------------------------------------------------
extern "C" void kernel_launch(void* const* d_in, const int* in_sizes, int n_in,
                              void* d_out, int out_size, void* d_ws, size_t ws_size,
                              hipStream_t stream) {
    const float* x     = (const float*)d_in[0];
    const float* w_p   = (const float*)d_in[1];
    const float* b_p   = (const float*)d_in[2];
    const float* w_m   = (const float*)d_in[3];
    const float* b_m   = (const float*)d_in[4];
    const float* w_d   = (const float*)d_in[5];
    const float* b_d   = (const float*)d_in[6];
    const float* gamma = (const float*)d_in[7];
    const float* beta  = (const float*)d_in[8];
    float* ws  = (float*)d_ws;
    float* y   = (float*)d_out;

    float* off  = ws + OFF_OFF;
    float* mask = ws + MASK_OFF;
    short* wt2  = (short*)(ws + WT_OFF);
    short* wpm2 = (short*)(ws + WPM_OFF);
    short* xh   = (short*)(ws + XH_OFF);
    float* sAB  = ws + SAB_OFF;
    float* gstat= ws + STAT_OFF;

    hipMemsetAsync(gstat, 0, 256 * sizeof(float), stream);
    k_nhwc<<<dim3(1024), dim3(256), 0, stream>>>(x, xh);
    k_pack<<<dim3((18 * 128 * 32 + 18 * 32 * 32) / 256), dim3(256), 0, stream>>>(w_d, w_p, w_m, wt2, wpm2);
    k_conv_pm<<<dim3(BB * HW / 32), dim3(256), 0, stream>>>(xh, wpm2, b_p, b_m, off, mask);
    k_deform<<<dim3(BB * HW / MPB), dim3(512), 0, stream>>>(xh, off, mask, wt2, b_d, y, gstat);
    k_finalize<<<dim3(1), dim3(128), 0, stream>>>(gstat, b_d, gamma, beta, sAB);
    k_norm_gelu<<<dim3((BB * COUT * HW / 4 + 255) / 256), dim3(256), 0, stream>>>(y, sAB);
}

// Round 7
// 124.089 us; speedup vs baseline: 1.2839x; 1.0089x over previous
//
#include <hip/hip_runtime.h>
#include <math.h>

#define BB 16
#define CIN 64
#define HH 64
#define WW 64
#define COUT 128
#define HW 4096          // HH*WW
#define CK 576           // CIN*9
#define CKP 584          // padded LDS stride (shorts): row stride 1168B = 4 banks mod 32 -> conflict-free phase-3 reads

typedef __attribute__((ext_vector_type(8))) short short8;
typedef __attribute__((ext_vector_type(4))) short short4v;
typedef __attribute__((ext_vector_type(4))) float f32x4;

// ---- workspace layout (float indices) ----
#define OFF_OFF   0                         // B*18*HW  = 1179648 floats
#define MASK_OFF  1179648                   // B*9*HW   = 589824 floats
#define WT_OFF    1769472                   // wt2: 18*128*32 shorts = 36864 floats
#define WPM_OFF   1806336                   // wpm2: 18*32*32 shorts = 9216 floats
#define XH_OFF    1815552                   // B*HW*CIN shorts = 8388608 floats
#define SAB_OFF   10204160                  // 256 floats (A,B per channel)
#define STAT_OFF  10204416                  // 256 floats (sum,sumsq accum)

__device__ __forceinline__ short f2bf(float f) {
    union { float f; unsigned u; } cv; cv.f = f;
    unsigned u = cv.u;
    unsigned r = (u + 0x7fffu + ((u >> 16) & 1u)) >> 16;
    return (short)r;
}
__device__ __forceinline__ float bf2f(short s) {
    union { unsigned u; float f; } cv;
    cv.u = ((unsigned)(unsigned short)s) << 16;
    return cv.f;
}

// ---------------------------------------------------------------------------
// Kernel A: transpose x NCHW -> NHWC bf16 (xh[b][y][x][c])
__global__ __launch_bounds__(256) void k_nhwc(const float* __restrict__ x,
                                              short* __restrict__ xh) {
    __shared__ float t[64][65];
    const int blk  = blockIdx.x;
    const int b    = blk >> 6;
    const int pos0 = (blk & 63) << 6;
    const int a    = threadIdx.x & 63;
    const int q    = threadIdx.x >> 6;
#pragma unroll
    for (int i = 0; i < 16; ++i) {
        int c = i * 4 + q;
        t[c][a] = x[((size_t)(b * CIN + c)) * HW + pos0 + a];
    }
    __syncthreads();
#pragma unroll
    for (int i = 0; i < 16; ++i) {
        int p = i * 4 + q;
        xh[((size_t)b * HW + pos0 + p) * CIN + a] = f2bf(t[a][p]);
    }
}

// ---------------------------------------------------------------------------
// Kernel B: pack weights to bf16, K-MAJOR panels.
__global__ __launch_bounds__(256) void k_pack(const float* __restrict__ wd,
                                              const float* __restrict__ wp,
                                              const float* __restrict__ wm,
                                              short* __restrict__ wt2,
                                              short* __restrict__ wpm2) {
    int i = blockIdx.x * 256 + threadIdx.x;
    if (i < 18 * 128 * 32) {
        int kc  = i >> 12;
        int rem = i & 4095;
        int co  = rem >> 5;
        int kl  = rem & 31;
        int kk  = kc * 32 + kl;
        int k   = kk >> 6;
        int c   = kk & 63;
        wt2[i] = f2bf(wd[co * CK + c * 9 + k]);
        return;
    }
    i -= 18 * 128 * 32;
    if (i < 18 * 32 * 32) {
        int kc  = i >> 10;
        int rem = i & 1023;
        int t   = rem >> 5;
        int kl  = rem & 31;
        int kk  = kc * 32 + kl;
        int k   = kk >> 6;
        int c   = kk & 63;
        float v = 0.f;
        if (t < 18)      v = wp[t * CK + c * 9 + k];
        else if (t < 27) v = wm[(t - 18) * CK + c * 9 + k];
        wpm2[i] = f2bf(v);
    }
}

// ---------------------------------------------------------------------------
// conv_pm A-fragment loader (constant-folds in unrolled loop)
__device__ __forceinline__ short8 conv_a(const short* __restrict__ xb,
                                         int ho, int wo, int lk, int kc) {
    const int k  = kc >> 1;
    const int c0 = (kc & 1) * 32 + lk * 8;
    const int yy = ho - 1 + k / 3;
    const int xx = wo - 1 + k % 3;
    const bool valid = ((unsigned)yy < 64u) & ((unsigned)xx < 64u);
    const int yyc = min(max(yy, 0), 63);
    const int xxc = min(max(xx, 0), 63);
    short8 a = *(const short8*)&xb[(((yyc << 6) + xxc) << 6) + c0];
    if (!valid) a = (short8)0;
    return a;
}

// ---------------------------------------------------------------------------
// Kernel 1: offset/mask conv, depth-2 pipelined MFMA K-loop.
__global__ __launch_bounds__(256) void k_conv_pm(const short* __restrict__ xh,
                                                 const short* __restrict__ wpm2,
                                                 const float* __restrict__ bp,
                                                 const float* __restrict__ bm,
                                                 float* __restrict__ off,
                                                 float* __restrict__ mask) {
    const int bid  = blockIdx.x;
    const int swz  = (bid & 7) * 256 + (bid >> 3);
    const int pos0 = swz * 32;
    const int b   = pos0 >> 12;
    const int ho  = (pos0 >> 6) & 63;
    const int wo0 = pos0 & 63;

    const int tid  = threadIdx.x;
    const int wv   = tid >> 6;
    const int lane = tid & 63;
    const int l15  = lane & 15;
    const int lk   = lane >> 4;
    const int mw   = wv & 1;
    const int nw   = wv >> 1;

    const int p    = mw * 16 + l15;
    const int wo   = wo0 + p;
    const int t    = nw * 16 + l15;

    const short* xb  = xh + (size_t)b * HW * CIN;
    const short* wr  = wpm2 + t * 32 + lk * 8;

    f32x4 acc = (f32x4)(0.f);
    short8 a_c = conv_a(xb, ho, wo, lk, 0);
    short8 b_c = *(const short8*)&wr[0];
#pragma unroll
    for (int kc = 0; kc < 18; ++kc) {
        short8 a_n{}, b_n{};
        if (kc < 17) {
            a_n = conv_a(xb, ho, wo, lk, kc + 1);
            b_n = *(const short8*)&wr[(kc + 1) * 1024];
        }
        acc = __builtin_amdgcn_mfma_f32_16x16x32_bf16(a_c, b_c, acc, 0, 0, 0);
        a_c = a_n; b_c = b_n;
    }

    const int pst = wo0 + mw * 16 + lk * 4;
    if (t < 18) {
        float bias = bp[t];
        float4 o;
        o.x = acc[0] + bias; o.y = acc[1] + bias;
        o.z = acc[2] + bias; o.w = acc[3] + bias;
        *(float4*)&off[(((size_t)b * 18 + t) * HH + ho) * WW + pst] = o;
    } else if (t < 27) {
        float bias = bm[t - 18];
        float4 o;
        o.x = 1.f / (1.f + expf(-(acc[0] + bias)));
        o.y = 1.f / (1.f + expf(-(acc[1] + bias)));
        o.z = 1.f / (1.f + expf(-(acc[2] + bias)));
        o.w = 1.f / (1.f + expf(-(acc[3] + bias)));
        *(float4*)&mask[(((size_t)b * 9 + (t - 18)) * HH + ho) * WW + pst] = o;
    }
}

// ---------------------------------------------------------------------------
// Kernel 2: deformable conv. 512 threads, depth-2 pipelines, fused BN partials.
#define MPB 32
__global__ __launch_bounds__(512) void k_deform(const short* __restrict__ xh,
                                                const float* __restrict__ off,
                                                const float* __restrict__ mask,
                                                const short* __restrict__ wt2,
                                                const float* __restrict__ bd,
                                                float* __restrict__ y,
                                                float* __restrict__ gstat) {
    __shared__ short     val[MPB * CKP];    // 37376 B
    __shared__ unsigned  s_yx[MPB * 9];     // 1152 B
    __shared__ _Float16  s_wh[MPB * 9 * 4]; // 2304 B  -> total 40832 B (<=40960: 4 blocks/CU if VGPR allows)

    const int bid  = blockIdx.x;
    const int swz  = (bid & 7) * 256 + (bid >> 3);     // XCD-chunked
    const int pos0 = swz * MPB;
    const int b   = pos0 >> 12;
    const int ho  = (pos0 >> 6) & 63;
    const int wo0 = pos0 & 63;
    const int tid = threadIdx.x;

    // phase 1: sampling parameters, coalesced (k = tid>>5 selects plane, p = tid&31 consecutive)
    if (tid < MPB * 9) {
        int k = tid >> 5;            // 0..8
        int p = tid & 31;
        int wo = wo0 + p;
        float dy = off[(((size_t)b * 18 + 2 * k    ) * HH + ho) * WW + wo];
        float dx = off[(((size_t)b * 18 + 2 * k + 1) * HH + ho) * WW + wo];
        float m  = mask[(((size_t)b * 9 + k) * HH + ho) * WW + wo];
        float py = (float)(ho - 1 + k / 3) + dy;
        float px = (float)(wo - 1 + k % 3) + dx;
        float fy = floorf(py), fx = floorf(px);
        float ly = py - fy, lx = px - fx;
        int y0 = (int)fy, x0 = (int)fx;
        int y1 = y0 + 1, x1 = x0 + 1;
        float vy0 = ((unsigned)y0 < 64u) ? 1.f : 0.f;
        float vy1 = ((unsigned)y1 < 64u) ? 1.f : 0.f;
        float vx0 = ((unsigned)x0 < 64u) ? 1.f : 0.f;
        float vx1 = ((unsigned)x1 < 64u) ? 1.f : 0.f;
        int y0c = min(max(y0, 0), 63), y1c = min(max(y1, 0), 63);
        int x0c = min(max(x0, 0), 63), x1c = min(max(x1, 0), 63);
        int tt = p * 9 + k;
        s_yx[tt] = (unsigned)y0c | ((unsigned)y1c << 8) | ((unsigned)x0c << 16) | ((unsigned)x1c << 24);
        s_wh[tt * 4 + 0] = (_Float16)((1.f - ly) * (1.f - lx) * m * vy0 * vx0);
        s_wh[tt * 4 + 1] = (_Float16)((1.f - ly) * lx * m * vy0 * vx1);
        s_wh[tt * 4 + 2] = (_Float16)(ly * (1.f - lx) * m * vy1 * vx0);
        s_wh[tt * 4 + 3] = (_Float16)(ly * lx * m * vy1 * vx1);
    }
    __syncthreads();

    // phase 2: gather, depth-2 software pipeline. 16 lanes per tap, lane li -> ch li*4..+3
    {
        const int g  = tid >> 4;            // 0..31
        const int li = tid & 15;
        const int c0 = li * 4;
        const short* xb = xh + (size_t)b * HW * CIN;

        int pr = g;
        unsigned yx_c = s_yx[pr];
        float w0_c = (float)s_wh[pr * 4 + 0], w1_c = (float)s_wh[pr * 4 + 1];
        float w2_c = (float)s_wh[pr * 4 + 2], w3_c = (float)s_wh[pr * 4 + 3];
        int y0 = yx_c & 255, y1 = (yx_c >> 8) & 255;
        int x0 = (yx_c >> 16) & 255, x1 = yx_c >> 24;
        short4v v00_c = *(const short4v*)&xb[(((y0 << 6) + x0) << 6) + c0];
        short4v v01_c = *(const short4v*)&xb[(((y0 << 6) + x1) << 6) + c0];
        short4v v10_c = *(const short4v*)&xb[(((y1 << 6) + x0) << 6) + c0];
        short4v v11_c = *(const short4v*)&xb[(((y1 << 6) + x1) << 6) + c0];

#pragma unroll
        for (int it = 0; it < 9; ++it) {
            unsigned yx_n = 0;
            float w0_n = 0.f, w1_n = 0.f, w2_n = 0.f, w3_n = 0.f;
            short4v v00_n{}, v01_n{}, v10_n{}, v11_n{};
            if (it < 8) {
                int prn = pr + 32;
                yx_n = s_yx[prn];
                w0_n = (float)s_wh[prn * 4 + 0]; w1_n = (float)s_wh[prn * 4 + 1];
                w2_n = (float)s_wh[prn * 4 + 2]; w3_n = (float)s_wh[prn * 4 + 3];
                int ny0 = yx_n & 255, ny1 = (yx_n >> 8) & 255;
                int nx0 = (yx_n >> 16) & 255, nx1 = yx_n >> 24;
                v00_n = *(const short4v*)&xb[(((ny0 << 6) + nx0) << 6) + c0];
                v01_n = *(const short4v*)&xb[(((ny0 << 6) + nx1) << 6) + c0];
                v10_n = *(const short4v*)&xb[(((ny1 << 6) + nx0) << 6) + c0];
                v11_n = *(const short4v*)&xb[(((ny1 << 6) + nx1) << 6) + c0];
            }
            // blend current
            int p = pr / 9, k = pr - p * 9;
            short4v o;
#pragma unroll
            for (int j = 0; j < 4; ++j) {
                float f = w0_c * bf2f(v00_c[j]) + w1_c * bf2f(v01_c[j])
                        + w2_c * bf2f(v10_c[j]) + w3_c * bf2f(v11_c[j]);
                o[j] = f2bf(f);
            }
            *(short4v*)&val[p * CKP + (k << 6) + c0] = o;
            // rotate
            pr += 32;
            yx_c = yx_n;
            w0_c = w0_n; w1_c = w1_n; w2_c = w2_n; w3_c = w3_n;
            v00_c = v00_n; v01_c = v01_n; v10_c = v10_n; v11_c = v11_n;
        }
    }
    __syncthreads();

    // phase 3: MFMA GEMM, depth-2 prefetch; wave = (pos half mw, channel quarter nq)
    const int wv   = tid >> 6;
    const int lane = tid & 63;
    const int l15  = lane & 15;
    const int lk   = lane >> 4;
    const int mw   = wv & 1;
    const int nq   = wv >> 1;

    f32x4 acc[2];
    acc[0] = (f32x4)(0.f);
    acc[1] = (f32x4)(0.f);

    const short* wq = wt2 + (nq * 32 + l15) * 32 + lk * 8;
    const int arow = (mw * 16 + l15) * CKP + lk * 8;

    short8 a_c  = *(const short8*)&val[arow];
    short8 b0_c = *(const short8*)&wq[0];
    short8 b1_c = *(const short8*)&wq[512];
#pragma unroll
    for (int kc = 0; kc < 18; ++kc) {
        short8 a_n{}, b0_n{}, b1_n{};
        if (kc < 17) {
            a_n  = *(const short8*)&val[arow + (kc + 1) * 32];
            b0_n = *(const short8*)&wq[(kc + 1) * 4096];
            b1_n = *(const short8*)&wq[(kc + 1) * 4096 + 512];
        }
        acc[0] = __builtin_amdgcn_mfma_f32_16x16x32_bf16(a_c, b0_c, acc[0], 0, 0, 0);
        acc[1] = __builtin_amdgcn_mfma_f32_16x16x32_bf16(a_c, b1_c, acc[1], 0, 0, 0);
        a_c = a_n; b0_c = b0_n; b1_c = b1_n;
    }

    // epilogue: write y (+bias), per-wave BN partials
    float s[2], q[2];
#pragma unroll
    for (int n = 0; n < 2; ++n) {
        int co = nq * 32 + n * 16 + l15;
        int p  = mw * 16 + lk * 4;
        float bias = bd[co];
        float4 o;
        o.x = acc[n][0] + bias;
        o.y = acc[n][1] + bias;
        o.z = acc[n][2] + bias;
        o.w = acc[n][3] + bias;
        *(float4*)&y[((size_t)(b * COUT + co)) * HW + ho * WW + wo0 + p] = o;
        float ls = acc[n][0] + acc[n][1] + acc[n][2] + acc[n][3];
        float lq = acc[n][0]*acc[n][0] + acc[n][1]*acc[n][1]
                 + acc[n][2]*acc[n][2] + acc[n][3]*acc[n][3];
        ls += __shfl_xor(ls, 16); ls += __shfl_xor(ls, 32);
        lq += __shfl_xor(lq, 16); lq += __shfl_xor(lq, 32);
        s[n] = ls; q[n] = lq;
    }
    float* scratch = (float*)val;             // val dead after barrier
    __syncthreads();
    if (mw == 0 && lane < 16) {
#pragma unroll
        for (int n = 0; n < 2; ++n) {
            int co = nq * 32 + n * 16 + l15;
            scratch[co]       = s[n];
            scratch[128 + co] = q[n];
        }
    }
    __syncthreads();
    if (mw == 1 && lane < 16) {
#pragma unroll
        for (int n = 0; n < 2; ++n) {
            int co = nq * 32 + n * 16 + l15;
            atomicAdd(&gstat[co],       s[n] + scratch[co]);
            atomicAdd(&gstat[128 + co], q[n] + scratch[128 + co]);
        }
    }
}

// ---------------------------------------------------------------------------
// Kernel 3: finalize BN scale/shift
__global__ __launch_bounds__(128) void k_finalize(const float* __restrict__ gstat,
                                                  const float* __restrict__ bd,
                                                  const float* __restrict__ gamma,
                                                  const float* __restrict__ beta,
                                                  float* __restrict__ sAB) {
    int c = threadIdx.x;
    const float invN = 1.f / (float)(BB * HW);
    float mean_acc = gstat[c] * invN;
    float var = gstat[128 + c] * invN - mean_acc * mean_acc;
    float mean_y = mean_acc + bd[c];
    float A = gamma[c] * rsqrtf(var + 1e-5f);
    sAB[c]       = A;
    sAB[128 + c] = beta[c] - mean_y * A;
}

// ---------------------------------------------------------------------------
// Kernel 4: normalize + exact GELU (in-place on d_out)
__global__ __launch_bounds__(256) void k_norm_gelu(float* __restrict__ y,
                                                   const float* __restrict__ sAB) {
    int i4 = blockIdx.x * 256 + threadIdx.x;
    if (i4 >= (BB * COUT * HW) / 4) return;
    int c = (i4 >> 10) & 127;
    float A  = sAB[c];
    float Bc = sAB[128 + c];
    float4 v = ((const float4*)y)[i4];
    float4 r;
    float t;
    t = v.x * A + Bc; r.x = 0.5f * t * (1.f + erff(t * 0.70710678118654752f));
    t = v.y * A + Bc; r.y = 0.5f * t * (1.f + erff(t * 0.70710678118654752f));
    t = v.z * A + Bc; r.z = 0.5f * t * (1.f + erff(t * 0.70710678118654752f));
    t = v.w * A + Bc; r.w = 0.5f * t * (1.f + erff(t * 0.70710678118654752f));
    ((float4*)y)[i4] = r;
}

// ---------------------------------------------------------------------------
extern "C" void kernel_launch(void* const* d_in, const int* in_sizes, int n_in,
                              void* d_out, int out_size, void* d_ws, size_t ws_size,
                              hipStream_t stream) {
    const float* x     = (const float*)d_in[0];
    const float* w_p   = (const float*)d_in[1];
    const float* b_p   = (const float*)d_in[2];
    const float* w_m   = (const float*)d_in[3];
    const float* b_m   = (const float*)d_in[4];
    const float* w_d   = (const float*)d_in[5];
    const float* b_d   = (const float*)d_in[6];
    const float* gamma = (const float*)d_in[7];
    const float* beta  = (const float*)d_in[8];
    float* ws  = (float*)d_ws;
    float* y   = (float*)d_out;

    float* off  = ws + OFF_OFF;
    float* mask = ws + MASK_OFF;
    short* wt2  = (short*)(ws + WT_OFF);
    short* wpm2 = (short*)(ws + WPM_OFF);
    short* xh   = (short*)(ws + XH_OFF);
    float* sAB  = ws + SAB_OFF;
    float* gstat= ws + STAT_OFF;

    hipMemsetAsync(gstat, 0, 256 * sizeof(float), stream);
    k_nhwc<<<dim3(1024), dim3(256), 0, stream>>>(x, xh);
    k_pack<<<dim3((18 * 128 * 32 + 18 * 32 * 32) / 256), dim3(256), 0, stream>>>(w_d, w_p, w_m, wt2, wpm2);
    k_conv_pm<<<dim3(BB * HW / 32), dim3(256), 0, stream>>>(xh, wpm2, b_p, b_m, off, mask);
    k_deform<<<dim3(BB * HW / MPB), dim3(512), 0, stream>>>(xh, off, mask, wt2, b_d, y, gstat);
    k_finalize<<<dim3(1), dim3(128), 0, stream>>>(gstat, b_d, gamma, beta, sAB);
    k_norm_gelu<<<dim3((BB * COUT * HW / 4 + 255) / 256), dim3(256), 0, stream>>>(y, sAB);
}

// Round 8
// 121.912 us; speedup vs baseline: 1.3069x; 1.0179x over previous
//
#include <hip/hip_runtime.h>
#include <math.h>

#define BB 16
#define CIN 64
#define HH 64
#define WW 64
#define COUT 128
#define HW 4096          // HH*WW
#define CK 576           // CIN*9
#define CKP 584          // padded LDS stride (shorts): 1168B row stride -> 2-way (free) on phase-3 reads

typedef __attribute__((ext_vector_type(8))) short short8;
typedef __attribute__((ext_vector_type(4))) short short4v;
typedef __attribute__((ext_vector_type(4))) float f32x4;

// ---- workspace layout (float indices) ----
#define OFF_OFF   0                         // B*18*HW  = 1179648 floats
#define MASK_OFF  1179648                   // B*9*HW   = 589824 floats
#define WT_OFF    1769472                   // wt2: 18*128*32 shorts = 36864 floats
#define WPM_OFF   1806336                   // wpm2: 18*32*32 shorts = 9216 floats
#define XH_OFF    1815552                   // B*HW*CIN shorts = 8388608 floats
#define SAB_OFF   10204160                  // 256 floats (A,B per channel)
#define STAT_OFF  10204416                  // 256 floats (sum,sumsq accum)

__device__ __forceinline__ short f2bf(float f) {
    union { float f; unsigned u; } cv; cv.f = f;
    unsigned u = cv.u;
    unsigned r = (u + 0x7fffu + ((u >> 16) & 1u)) >> 16;
    return (short)r;
}
__device__ __forceinline__ float bf2f(short s) {
    union { unsigned u; float f; } cv;
    cv.u = ((unsigned)(unsigned short)s) << 16;
    return cv.f;
}

// ---------------------------------------------------------------------------
// Kernel A: transpose x NCHW -> NHWC bf16 (xh[b][y][x][c])
__global__ __launch_bounds__(256) void k_nhwc(const float* __restrict__ x,
                                              short* __restrict__ xh) {
    __shared__ float t[64][65];
    const int blk  = blockIdx.x;
    const int b    = blk >> 6;
    const int pos0 = (blk & 63) << 6;
    const int a    = threadIdx.x & 63;
    const int q    = threadIdx.x >> 6;
#pragma unroll
    for (int i = 0; i < 16; ++i) {
        int c = i * 4 + q;
        t[c][a] = x[((size_t)(b * CIN + c)) * HW + pos0 + a];
    }
    __syncthreads();
#pragma unroll
    for (int i = 0; i < 16; ++i) {
        int p = i * 4 + q;
        xh[((size_t)b * HW + pos0 + p) * CIN + a] = f2bf(t[a][p]);
    }
}

// ---------------------------------------------------------------------------
// Kernel B: pack weights to bf16, K-MAJOR panels.
__global__ __launch_bounds__(256) void k_pack(const float* __restrict__ wd,
                                              const float* __restrict__ wp,
                                              const float* __restrict__ wm,
                                              short* __restrict__ wt2,
                                              short* __restrict__ wpm2) {
    int i = blockIdx.x * 256 + threadIdx.x;
    if (i < 18 * 128 * 32) {
        int kc  = i >> 12;
        int rem = i & 4095;
        int co  = rem >> 5;
        int kl  = rem & 31;
        int kk  = kc * 32 + kl;
        int k   = kk >> 6;
        int c   = kk & 63;
        wt2[i] = f2bf(wd[co * CK + c * 9 + k]);
        return;
    }
    i -= 18 * 128 * 32;
    if (i < 18 * 32 * 32) {
        int kc  = i >> 10;
        int rem = i & 1023;
        int t   = rem >> 5;
        int kl  = rem & 31;
        int kk  = kc * 32 + kl;
        int k   = kk >> 6;
        int c   = kk & 63;
        float v = 0.f;
        if (t < 18)      v = wp[t * CK + c * 9 + k];
        else if (t < 27) v = wm[(t - 18) * CK + c * 9 + k];
        wpm2[i] = f2bf(v);
    }
}

// ---------------------------------------------------------------------------
// conv_pm A-fragment loader
__device__ __forceinline__ short8 conv_a(const short* __restrict__ xb,
                                         int ho, int wo, int lk, int kc) {
    const int k  = kc >> 1;
    const int c0 = (kc & 1) * 32 + lk * 8;
    const int yy = ho - 1 + k / 3;
    const int xx = wo - 1 + k % 3;
    const bool valid = ((unsigned)yy < 64u) & ((unsigned)xx < 64u);
    const int yyc = min(max(yy, 0), 63);
    const int xxc = min(max(xx, 0), 63);
    short8 a = *(const short8*)&xb[(((yyc << 6) + xxc) << 6) + c0];
    if (!valid) a = (short8)0;
    return a;
}

// ---------------------------------------------------------------------------
// Kernel 1: offset/mask conv — ALL A and B fragments preloaded into register
// arrays (forced ILP), then 18 back-to-back MFMAs.
__global__ __launch_bounds__(256, 2) void k_conv_pm(const short* __restrict__ xh,
                                                    const short* __restrict__ wpm2,
                                                    const float* __restrict__ bp,
                                                    const float* __restrict__ bm,
                                                    float* __restrict__ off,
                                                    float* __restrict__ mask) {
    const int bid  = blockIdx.x;
    const int swz  = (bid & 7) * 256 + (bid >> 3);
    const int pos0 = swz * 32;
    const int b   = pos0 >> 12;
    const int ho  = (pos0 >> 6) & 63;
    const int wo0 = pos0 & 63;

    const int tid  = threadIdx.x;
    const int wv   = tid >> 6;
    const int lane = tid & 63;
    const int l15  = lane & 15;
    const int lk   = lane >> 4;
    const int mw   = wv & 1;
    const int nw   = wv >> 1;

    const int p    = mw * 16 + l15;
    const int wo   = wo0 + p;
    const int t    = nw * 16 + l15;

    const short* xb  = xh + (size_t)b * HW * CIN;
    const short* wr  = wpm2 + t * 32 + lk * 8;

    short8 ar[18], brr[18];
#pragma unroll
    for (int kc = 0; kc < 18; ++kc) {
        ar[kc]  = conv_a(xb, ho, wo, lk, kc);
        brr[kc] = *(const short8*)&wr[kc * 1024];
    }
    f32x4 acc = (f32x4)(0.f);
#pragma unroll
    for (int kc = 0; kc < 18; ++kc)
        acc = __builtin_amdgcn_mfma_f32_16x16x32_bf16(ar[kc], brr[kc], acc, 0, 0, 0);

    const int pst = wo0 + mw * 16 + lk * 4;
    if (t < 18) {
        float bias = bp[t];
        float4 o;
        o.x = acc[0] + bias; o.y = acc[1] + bias;
        o.z = acc[2] + bias; o.w = acc[3] + bias;
        *(float4*)&off[(((size_t)b * 18 + t) * HH + ho) * WW + pst] = o;
    } else if (t < 27) {
        float bias = bm[t - 18];
        float4 o;
        o.x = 1.f / (1.f + expf(-(acc[0] + bias)));
        o.y = 1.f / (1.f + expf(-(acc[1] + bias)));
        o.z = 1.f / (1.f + expf(-(acc[2] + bias)));
        o.w = 1.f / (1.f + expf(-(acc[3] + bias)));
        *(float4*)&mask[(((size_t)b * 9 + (t - 18)) * HH + ho) * WW + pst] = o;
    }
}

// ---------------------------------------------------------------------------
// Kernel 2: deformable conv. 512 threads. Register-array forced ILP:
//  phase 2: all 36 corner loads in flight, then blend.
//  phase 3: wave owns 16 co (no B duplication); all 18 B-frags preloaded
//           to registers, K-loop is ds_read+MFMA only.
#define MPB 32
__global__ __launch_bounds__(512, 2) void k_deform(const short* __restrict__ xh,
                                                   const float* __restrict__ off,
                                                   const float* __restrict__ mask,
                                                   const short* __restrict__ wt2,
                                                   const float* __restrict__ bd,
                                                   float* __restrict__ y,
                                                   float* __restrict__ gstat) {
    __shared__ short     val[MPB * CKP];    // 37376 B
    __shared__ unsigned  s_yx[MPB * 9];     // 1152 B
    __shared__ _Float16  s_wh[MPB * 9 * 4]; // 2304 B

    const int bid  = blockIdx.x;
    const int swz  = (bid & 7) * 256 + (bid >> 3);     // XCD-chunked
    const int pos0 = swz * MPB;
    const int b   = pos0 >> 12;
    const int ho  = (pos0 >> 6) & 63;
    const int wo0 = pos0 & 63;
    const int tid = threadIdx.x;

    // phase 1: sampling parameters, coalesced
    if (tid < MPB * 9) {
        int k = tid >> 5;
        int p = tid & 31;
        int wo = wo0 + p;
        float dy = off[(((size_t)b * 18 + 2 * k    ) * HH + ho) * WW + wo];
        float dx = off[(((size_t)b * 18 + 2 * k + 1) * HH + ho) * WW + wo];
        float m  = mask[(((size_t)b * 9 + k) * HH + ho) * WW + wo];
        float py = (float)(ho - 1 + k / 3) + dy;
        float px = (float)(wo - 1 + k % 3) + dx;
        float fy = floorf(py), fx = floorf(px);
        float ly = py - fy, lx = px - fx;
        int y0 = (int)fy, x0 = (int)fx;
        int y1 = y0 + 1, x1 = x0 + 1;
        float vy0 = ((unsigned)y0 < 64u) ? 1.f : 0.f;
        float vy1 = ((unsigned)y1 < 64u) ? 1.f : 0.f;
        float vx0 = ((unsigned)x0 < 64u) ? 1.f : 0.f;
        float vx1 = ((unsigned)x1 < 64u) ? 1.f : 0.f;
        int y0c = min(max(y0, 0), 63), y1c = min(max(y1, 0), 63);
        int x0c = min(max(x0, 0), 63), x1c = min(max(x1, 0), 63);
        int tt = p * 9 + k;
        s_yx[tt] = (unsigned)y0c | ((unsigned)y1c << 8) | ((unsigned)x0c << 16) | ((unsigned)x1c << 24);
        s_wh[tt * 4 + 0] = (_Float16)((1.f - ly) * (1.f - lx) * m * vy0 * vx0);
        s_wh[tt * 4 + 1] = (_Float16)((1.f - ly) * lx * m * vy0 * vx1);
        s_wh[tt * 4 + 2] = (_Float16)(ly * (1.f - lx) * m * vy1 * vx0);
        s_wh[tt * 4 + 3] = (_Float16)(ly * lx * m * vy1 * vx1);
    }
    __syncthreads();

    // phase 2: issue ALL 36 corner loads, then blend + ds_write.
    {
        const int g  = tid >> 4;            // 0..31 tap-groups
        const int li = tid & 15;
        const int c0 = li * 4;
        const short* xb = xh + (size_t)b * HW * CIN;

        short4v v[9][4];
#pragma unroll
        for (int it = 0; it < 9; ++it) {
            int pr = it * 32 + g;
            unsigned yx = s_yx[pr];
            int y0 = yx & 255, y1 = (yx >> 8) & 255;
            int x0 = (yx >> 16) & 255, x1 = yx >> 24;
            v[it][0] = *(const short4v*)&xb[(((y0 << 6) + x0) << 6) + c0];
            v[it][1] = *(const short4v*)&xb[(((y0 << 6) + x1) << 6) + c0];
            v[it][2] = *(const short4v*)&xb[(((y1 << 6) + x0) << 6) + c0];
            v[it][3] = *(const short4v*)&xb[(((y1 << 6) + x1) << 6) + c0];
        }
#pragma unroll
        for (int it = 0; it < 9; ++it) {
            int pr = it * 32 + g;
            int p = pr / 9, k = pr - p * 9;
            float w0 = (float)s_wh[pr * 4 + 0], w1 = (float)s_wh[pr * 4 + 1];
            float w2 = (float)s_wh[pr * 4 + 2], w3 = (float)s_wh[pr * 4 + 3];
            short4v o;
#pragma unroll
            for (int j = 0; j < 4; ++j) {
                float f = w0 * bf2f(v[it][0][j]) + w1 * bf2f(v[it][1][j])
                        + w2 * bf2f(v[it][2][j]) + w3 * bf2f(v[it][3][j]);
                o[j] = f2bf(f);
            }
            *(short4v*)&val[p * CKP + (k << 6) + c0] = o;
        }
    }
    __syncthreads();

    // phase 3: wave wv owns co = wv*16..wv*16+15 (disjoint); B fully in registers.
    const int wv   = tid >> 6;
    const int lane = tid & 63;
    const int l15  = lane & 15;
    const int lk   = lane >> 4;
    const int co   = wv * 16 + l15;

    short8 br[18];
    {
        const short* wq = wt2 + (size_t)co * 32 + lk * 8;
#pragma unroll
        for (int kc = 0; kc < 18; ++kc)
            br[kc] = *(const short8*)&wq[kc * 4096];
    }

    f32x4 acc0 = (f32x4)(0.f);
    f32x4 acc1 = (f32x4)(0.f);
    const int arow = l15 * CKP + lk * 8;
#pragma unroll
    for (int kc = 0; kc < 18; ++kc) {
        short8 a0 = *(const short8*)&val[arow + kc * 32];
        short8 a1 = *(const short8*)&val[arow + 16 * CKP + kc * 32];
        acc0 = __builtin_amdgcn_mfma_f32_16x16x32_bf16(a0, br[kc], acc0, 0, 0, 0);
        acc1 = __builtin_amdgcn_mfma_f32_16x16x32_bf16(a1, br[kc], acc1, 0, 0, 0);
    }

    // epilogue: y writes (+bias) and fused BN partials (wave owns its co's)
    {
        float bias = bd[co];
        float4 o;
        o.x = acc0[0] + bias; o.y = acc0[1] + bias;
        o.z = acc0[2] + bias; o.w = acc0[3] + bias;
        *(float4*)&y[((size_t)(b * COUT + co)) * HW + ho * WW + wo0 + lk * 4] = o;
        o.x = acc1[0] + bias; o.y = acc1[1] + bias;
        o.z = acc1[2] + bias; o.w = acc1[3] + bias;
        *(float4*)&y[((size_t)(b * COUT + co)) * HW + ho * WW + wo0 + 16 + lk * 4] = o;
    }
    float ls = acc0[0] + acc0[1] + acc0[2] + acc0[3]
             + acc1[0] + acc1[1] + acc1[2] + acc1[3];
    float lq = acc0[0]*acc0[0] + acc0[1]*acc0[1] + acc0[2]*acc0[2] + acc0[3]*acc0[3]
             + acc1[0]*acc1[0] + acc1[1]*acc1[1] + acc1[2]*acc1[2] + acc1[3]*acc1[3];
    ls += __shfl_xor(ls, 16); ls += __shfl_xor(ls, 32);
    lq += __shfl_xor(lq, 16); lq += __shfl_xor(lq, 32);
    if (lane < 16) {
        atomicAdd(&gstat[wv * 16 + lane],       ls);
        atomicAdd(&gstat[128 + wv * 16 + lane], lq);
    }
}

// ---------------------------------------------------------------------------
// Kernel 3: finalize BN scale/shift
__global__ __launch_bounds__(128) void k_finalize(const float* __restrict__ gstat,
                                                  const float* __restrict__ bd,
                                                  const float* __restrict__ gamma,
                                                  const float* __restrict__ beta,
                                                  float* __restrict__ sAB) {
    int c = threadIdx.x;
    const float invN = 1.f / (float)(BB * HW);
    float mean_acc = gstat[c] * invN;
    float var = gstat[128 + c] * invN - mean_acc * mean_acc;
    float mean_y = mean_acc + bd[c];
    float A = gamma[c] * rsqrtf(var + 1e-5f);
    sAB[c]       = A;
    sAB[128 + c] = beta[c] - mean_y * A;
}

// ---------------------------------------------------------------------------
// Kernel 4: normalize + exact GELU (in-place on d_out)
__global__ __launch_bounds__(256) void k_norm_gelu(float* __restrict__ y,
                                                   const float* __restrict__ sAB) {
    int i4 = blockIdx.x * 256 + threadIdx.x;
    if (i4 >= (BB * COUT * HW) / 4) return;
    int c = (i4 >> 10) & 127;
    float A  = sAB[c];
    float Bc = sAB[128 + c];
    float4 v = ((const float4*)y)[i4];
    float4 r;
    float t;
    t = v.x * A + Bc; r.x = 0.5f * t * (1.f + erff(t * 0.70710678118654752f));
    t = v.y * A + Bc; r.y = 0.5f * t * (1.f + erff(t * 0.70710678118654752f));
    t = v.z * A + Bc; r.z = 0.5f * t * (1.f + erff(t * 0.70710678118654752f));
    t = v.w * A + Bc; r.w = 0.5f * t * (1.f + erff(t * 0.70710678118654752f));
    ((float4*)y)[i4] = r;
}

// ---------------------------------------------------------------------------
extern "C" void kernel_launch(void* const* d_in, const int* in_sizes, int n_in,
                              void* d_out, int out_size, void* d_ws, size_t ws_size,
                              hipStream_t stream) {
    const float* x     = (const float*)d_in[0];
    const float* w_p   = (const float*)d_in[1];
    const float* b_p   = (const float*)d_in[2];
    const float* w_m   = (const float*)d_in[3];
    const float* b_m   = (const float*)d_in[4];
    const float* w_d   = (const float*)d_in[5];
    const float* b_d   = (const float*)d_in[6];
    const float* gamma = (const float*)d_in[7];
    const float* beta  = (const float*)d_in[8];
    float* ws  = (float*)d_ws;
    float* y   = (float*)d_out;

    float* off  = ws + OFF_OFF;
    float* mask = ws + MASK_OFF;
    short* wt2  = (short*)(ws + WT_OFF);
    short* wpm2 = (short*)(ws + WPM_OFF);
    short* xh   = (short*)(ws + XH_OFF);
    float* sAB  = ws + SAB_OFF;
    float* gstat= ws + STAT_OFF;

    hipMemsetAsync(gstat, 0, 256 * sizeof(float), stream);
    k_nhwc<<<dim3(1024), dim3(256), 0, stream>>>(x, xh);
    k_pack<<<dim3((18 * 128 * 32 + 18 * 32 * 32) / 256), dim3(256), 0, stream>>>(w_d, w_p, w_m, wt2, wpm2);
    k_conv_pm<<<dim3(BB * HW / 32), dim3(256), 0, stream>>>(xh, wpm2, b_p, b_m, off, mask);
    k_deform<<<dim3(BB * HW / MPB), dim3(512), 0, stream>>>(xh, off, mask, wt2, b_d, y, gstat);
    k_finalize<<<dim3(1), dim3(128), 0, stream>>>(gstat, b_d, gamma, beta, sAB);
    k_norm_gelu<<<dim3((BB * COUT * HW / 4 + 255) / 256), dim3(256), 0, stream>>>(y, sAB);
}